// Round 3
// baseline (3009.786 us; speedup 1.0000x reference)
//
#include <hip/hip_runtime.h>
#include <hip/hip_bf16.h>

// Masked-reset LSTM, segment-parallel formulation.
//
// Dims (fixed by the reference):
//   OBS=64, EMBED=128, HIDDEN=256, B=32, T=2048, N=B*T=65536
//
// Key ideas:
//  1. Fold embedding into the gate GEMM: z = obs @ (W_embed@kernel) + h @ rec + (bias + b_embed@kernel)
//     -> combined weight Wg[320][1024] (rows 0..63 = obs part, 64..319 = recurrent part),
//        stored permuted as Wg[k][j][gate] so thread j loads one float4 = its 4 gate weights.
//  2. Episode resets (m=1) zero the state -> each (b) chain splits into independent segments.
//     Extract segments on device, counting-sort longest-first, dynamically schedule onto
//     256 WGs x 16 slots. All slots in a WG advance in lockstep sharing weight loads (16x L2 reuse).
//  3. Slot compaction to a prefix + switch on active-count -> tail (few long segments) runs at
//     cost proportional to active slots.
//
// R1 fix: race in step_n — h was written into X while other waves were still
// reading X for their accumulation. Now: gates -> registers, uniform
// __syncthreads(), then write-back. Output is bitwise deterministic across
// replays (scheduling order does not change any segment's arithmetic).
// R2: resubmit unchanged (R1 bench was GPUAcquisitionTimeout — no data).

#define T_SEQ   2048
#define NBATCH  32
#define OBS     64
#define HID     256
#define KROWS   320          // 64 obs + 256 hidden
#define GSLOTS  16
#define XPAD    324          // X row stride in floats; 324*4 = 1296 bytes, 16B aligned
#define MAXSEG  65536

// ---------------- math helpers ----------------
__device__ __forceinline__ float sigm(float x) {
    x = fminf(fmaxf(x, -30.f), 30.f);
    return 1.f / (1.f + __expf(-x));
}
__device__ __forceinline__ float tanh_(float x) {
    x = fminf(fmaxf(x, -15.f), 15.f);
    float e = __expf(2.f * x);
    return (e - 1.f) / (e + 1.f);
}

// ---------------- prep: build Wg, bc4, init counters ----------------
__global__ void prep_kernel(const float* __restrict__ W_embed, const float* __restrict__ b_embed,
                            const float* __restrict__ kern,    const float* __restrict__ rec,
                            const float* __restrict__ bias,
                            float* __restrict__ Wg, float* __restrict__ bc4, unsigned* __restrict__ cnt) {
    int bi = blockIdx.x, tid = threadIdx.x;
    if (bi < 256) {
        int r = bi >> 2;
        int c = ((bi & 3) << 8) + tid;
        float acc = 0.f;
        #pragma unroll 8
        for (int k = 0; k < 128; ++k)
            acc = fmaf(W_embed[r * 128 + k], kern[k * 1024 + c], acc);
        Wg[(r * 256 + (c & 255)) * 4 + (c >> 8)] = acc;
    } else if (bi < 512) {
        int k = bi - 256;
        #pragma unroll
        for (int p = 0; p < 4; ++p) {
            int c = (p << 8) + tid;
            Wg[((64 + k) * 256 + (c & 255)) * 4 + (c >> 8)] = rec[k * 1024 + c];
        }
    } else if (bi == 512) {
        #pragma unroll
        for (int p = 0; p < 4; ++p) {
            int c = (p << 8) + tid;
            float acc = bias[c];
            for (int k = 0; k < 128; ++k)
                acc = fmaf(b_embed[k], kern[k * 1024 + c], acc);
            bc4[(c & 255) * 4 + (c >> 8)] = acc;
        }
    } else {
        if (tid < 16) cnt[tid] = 0u;
    }
}

// ---------------- segment extraction ----------------
// A segment starts at t==0 or wherever m!=0; it runs until the next start.
__global__ void seg_kernel(const float* __restrict__ M, uint2* __restrict__ segs,
                           unsigned* __restrict__ cnt) {
    int b = blockIdx.x, tid = threadIdx.x;
    int base = b * T_SEQ;
    for (int t = tid; t < T_SEQ; t += 256) {
        bool start = (t == 0) || (M[base + t] != 0.f);
        if (!start) continue;
        int t2 = t + 1;
        while (t2 < T_SEQ && M[base + t2] == 0.f) ++t2;
        unsigned idx = atomicAdd(&cnt[0], 1u);
        segs[idx] = make_uint2((unsigned)(base + t), (unsigned)(t2 - t));
    }
}

// ---------------- counting sort by length, descending ----------------
__global__ void sort_kernel(const uint2* __restrict__ segs, uint2* __restrict__ out,
                            unsigned* __restrict__ cnt) {
    __shared__ unsigned hist[2049];
    __shared__ unsigned partial[256];
    __shared__ unsigned ofs[2049];
    int tid = threadIdx.x;
    unsigned n = cnt[0];
    for (int i = tid; i < 2049; i += 256) hist[i] = 0u;
    __syncthreads();
    for (unsigned i = tid; i < n; i += 256) atomicAdd(&hist[segs[i].y], 1u);
    __syncthreads();
    // bins 1..2048; thread t covers bins t*8+1 .. t*8+8
    int cs = tid * 8 + 1;
    unsigned s = 0;
    #pragma unroll
    for (int i = 0; i < 8; ++i) s += hist[cs + i];
    partial[tid] = s;
    __syncthreads();
    if (tid == 0) {
        unsigned run = 0;
        for (int t = 255; t >= 0; --t) { unsigned p = partial[t]; partial[t] = run; run += p; }
    }
    __syncthreads();
    unsigned run = partial[tid];
    #pragma unroll
    for (int i = 7; i >= 0; --i) { int bin = cs + i; ofs[bin] = run; run += hist[bin]; }
    __syncthreads();
    for (unsigned i = tid; i < n; i += 256) {
        uint2 sg = segs[i];
        unsigned pos = atomicAdd(&ofs[sg.y], 1u);
        out[pos] = sg;
    }
}

// ---------------- one lockstep step for N active slots ----------------
template <int N>
__device__ __forceinline__ void step_n(float (*X)[XPAD], float (*C)[HID],
                                       const float* __restrict__ Wg,
                                       const float* __restrict__ bc4,
                                       const unsigned* __restrict__ ssn,
                                       float* __restrict__ out, int tid) {
    const float4* __restrict__ W4 = (const float4*)Wg;
    float4 acc[N];
    const float4 bcv = ((const float4*)bc4)[tid];
    #pragma unroll
    for (int g = 0; g < N; ++g) acc[g] = bcv;

    for (int k4 = 0; k4 < KROWS / 4; ++k4) {
        float4 w[4];
        #pragma unroll
        for (int i = 0; i < 4; ++i) w[i] = W4[(k4 * 4 + i) * 256 + tid];
        #pragma unroll
        for (int g = 0; g < N; ++g) {
            const float4 xv = *(const float4*)&X[g][k4 * 4];
            float xs0 = xv.x, xs1 = xv.y, xs2 = xv.z, xs3 = xv.w;
            acc[g].x = fmaf(xs0, w[0].x, acc[g].x);
            acc[g].y = fmaf(xs0, w[0].y, acc[g].y);
            acc[g].z = fmaf(xs0, w[0].z, acc[g].z);
            acc[g].w = fmaf(xs0, w[0].w, acc[g].w);
            acc[g].x = fmaf(xs1, w[1].x, acc[g].x);
            acc[g].y = fmaf(xs1, w[1].y, acc[g].y);
            acc[g].z = fmaf(xs1, w[1].z, acc[g].z);
            acc[g].w = fmaf(xs1, w[1].w, acc[g].w);
            acc[g].x = fmaf(xs2, w[2].x, acc[g].x);
            acc[g].y = fmaf(xs2, w[2].y, acc[g].y);
            acc[g].z = fmaf(xs2, w[2].z, acc[g].z);
            acc[g].w = fmaf(xs2, w[2].w, acc[g].w);
            acc[g].x = fmaf(xs3, w[3].x, acc[g].x);
            acc[g].y = fmaf(xs3, w[3].y, acc[g].y);
            acc[g].z = fmaf(xs3, w[3].z, acc[g].z);
            acc[g].w = fmaf(xs3, w[3].w, acc[g].w);
        }
    }
    // gates -> registers only (no shared writes yet)
    float hv[N], cv[N];
    #pragma unroll
    for (int g = 0; g < N; ++g) {
        float i = sigm(acc[g].x);
        float f = sigm(acc[g].y);
        float gg = tanh_(acc[g].z);
        float o = sigm(acc[g].w);
        float c = fmaf(f, C[g][tid], i * gg);   // C[g][tid] is thread-private
        hv[g] = o * tanh_(c);
        cv[g] = c;
    }
    __syncthreads();   // all X reads (k-loop) complete before overwriting X
    #pragma unroll
    for (int g = 0; g < N; ++g) {
        C[g][tid] = cv[g];
        X[g][OBS + tid] = hv[g];
        out[(size_t)ssn[g] * HID + tid] = hv[g];
    }
}

// ---------------- persistent segment-parallel LSTM ----------------
__launch_bounds__(256)
__global__ void lstm_kernel(const float* __restrict__ obs, const float* __restrict__ S,
                            const float* __restrict__ M,
                            const float* __restrict__ Wg, const float* __restrict__ bc4,
                            const uint2* __restrict__ segs, unsigned* __restrict__ cnt,
                            float* __restrict__ out) {
    __shared__ float X[GSLOTS][XPAD];     // per slot: [0..63]=obs row, [64..319]=h
    __shared__ float C[GSLOTS][HID];      // cell state
    __shared__ unsigned ssn[GSLOTS], send[GSLOTS];
    __shared__ int   sact[GSLOTS], sfresh[GSLOTS];
    __shared__ float smg[GSLOTS];
    __shared__ int   sh_nact, sh_nmig;
    __shared__ unsigned sh_mask;
    __shared__ int   msrc[GSLOTS], mdst[GSLOTS];

    const int tid = threadIdx.x;
    const unsigned nseg = cnt[0];
    if (tid < GSLOTS) sact[tid] = 0;
    __syncthreads();

    for (;;) {
        // ---- lane phase: advance / finish / refill (keeps prefix while queue nonempty)
        if (tid < GSLOTS) {
            int g = tid;
            if (sact[g]) {
                unsigned nn = ssn[g] + 1;
                if (nn >= send[g]) sact[g] = 0; else ssn[g] = nn;
            }
            sfresh[g] = 0;
            if (!sact[g]) {
                unsigned idx = atomicAdd(&cnt[1], 1u);
                if (idx < nseg) {
                    uint2 sg = segs[idx];
                    ssn[g] = sg.x; send[g] = sg.x + sg.y;
                    sact[g] = 1; sfresh[g] = 1;
                }
            }
        }
        if (tid < 64) {
            unsigned long long bal = __ballot(tid < GSLOTS && sact[tid]);
            if (tid == 0) {
                unsigned m = (unsigned)(bal & 0xFFFFull);
                sh_mask = m;
                sh_nact = __popc(m);
            }
        }
        __syncthreads();                       // A
        const unsigned mask = sh_mask;
        if (mask == 0u) break;
        const int nact = sh_nact;

        // ---- compaction to prefix (rare; only when refill failed mid-set)
        if (mask != ((1u << nact) - 1u)) {
            if (tid == 0) {
                int w = 0, nm = 0;
                for (int g = 0; g < GSLOTS; ++g) if (sact[g]) {
                    if (g != w) {
                        msrc[nm] = g; mdst[nm] = w; ++nm;
                        ssn[w] = ssn[g]; send[w] = send[g];
                        sfresh[w] = sfresh[g];
                        sact[w] = 1; sact[g] = 0;
                    }
                    ++w;
                }
                sh_nmig = nm;
            }
            __syncthreads();
            const int nm = sh_nmig;
            for (int i = 0; i < nm; ++i) {     // per-element same-thread moves: race-free
                int s = msrc[i], d = mdst[i];
                X[d][tid] = X[s][tid];
                if (tid + 256 < XPAD) X[d][tid + 256] = X[s][tid + 256];
                C[d][tid] = C[s][tid];
            }
            __syncthreads();
        }

        // ---- per-step loads: mask, fresh-state init, obs rows
        if (tid < GSLOTS) {
            int g = tid;
            smg[g] = (g < nact) ? M[ssn[g]] : 0.f;
        }
        for (int g = 0; g < nact; ++g) {
            if (sfresh[g]) {
                unsigned n0 = ssn[g];
                if ((n0 & (T_SEQ - 1)) == 0u) {       // chain start: state = S[b]
                    unsigned b = n0 >> 11;
                    X[g][OBS + tid] = S[b * 512 + tid];
                    C[g][tid]       = S[b * 512 + 256 + tid];
                } else {                               // segment start at reset: zero
                    X[g][OBS + tid] = 0.f;
                    C[g][tid]       = 0.f;
                }
            }
        }
        {
            int g = (tid >> 6);
            int e = tid & 63;
            #pragma unroll
            for (int p = 0; p < 4; ++p, g += 4)
                if (g < nact) X[g][e] = obs[(size_t)ssn[g] * OBS + e];
        }
        __syncthreads();                       // B

        // ---- episode reset (m=1 -> zero state before the step)
        for (int g = 0; g < nact; ++g) {
            if (smg[g] != 0.f) { X[g][OBS + tid] = 0.f; C[g][tid] = 0.f; }
        }
        __syncthreads();                       // C

        // ---- lockstep GEMM + gates for the active prefix
        switch (nact) {
            case 1:  step_n<1>(X, C, Wg, bc4, ssn, out, tid); break;
            case 2:  step_n<2>(X, C, Wg, bc4, ssn, out, tid); break;
            case 3:  step_n<3>(X, C, Wg, bc4, ssn, out, tid); break;
            case 4:  step_n<4>(X, C, Wg, bc4, ssn, out, tid); break;
            case 5:  step_n<5>(X, C, Wg, bc4, ssn, out, tid); break;
            case 6:  step_n<6>(X, C, Wg, bc4, ssn, out, tid); break;
            case 7:  step_n<7>(X, C, Wg, bc4, ssn, out, tid); break;
            case 8:  step_n<8>(X, C, Wg, bc4, ssn, out, tid); break;
            case 9:  step_n<9>(X, C, Wg, bc4, ssn, out, tid); break;
            case 10: step_n<10>(X, C, Wg, bc4, ssn, out, tid); break;
            case 11: step_n<11>(X, C, Wg, bc4, ssn, out, tid); break;
            case 12: step_n<12>(X, C, Wg, bc4, ssn, out, tid); break;
            case 13: step_n<13>(X, C, Wg, bc4, ssn, out, tid); break;
            case 14: step_n<14>(X, C, Wg, bc4, ssn, out, tid); break;
            case 15: step_n<15>(X, C, Wg, bc4, ssn, out, tid); break;
            default: step_n<16>(X, C, Wg, bc4, ssn, out, tid); break;
        }
        __syncthreads();                       // D
    }
}

// ---------------- launch ----------------
extern "C" void kernel_launch(void* const* d_in, const int* in_sizes, int n_in,
                              void* d_out, int out_size, void* d_ws, size_t ws_size,
                              hipStream_t stream) {
    const float* obs     = (const float*)d_in[0];
    const float* S       = (const float*)d_in[1];
    const float* M       = (const float*)d_in[2];
    const float* W_embed = (const float*)d_in[3];
    const float* b_embed = (const float*)d_in[4];
    const float* kern    = (const float*)d_in[5];
    const float* rec     = (const float*)d_in[6];
    const float* bias    = (const float*)d_in[7];
    float* out = (float*)d_out;

    // ws layout (fp32 elems): Wg[320*1024] | bc4[1024] | cnt[16 u32] | segs[MAXSEG uint2] | sorted[MAXSEG uint2]
    float*    ws    = (float*)d_ws;
    float*    Wg    = ws;
    float*    bc4   = Wg + 320 * 1024;
    unsigned* cnt   = (unsigned*)(bc4 + 1024);
    uint2*    segs  = (uint2*)(cnt + 16);
    uint2*    ssort = segs + MAXSEG;
    // total: 1,314,880 + 2*524,288 bytes ~= 2.4 MB

    hipLaunchKernelGGL(prep_kernel, dim3(514), dim3(256), 0, stream,
                       W_embed, b_embed, kern, rec, bias, Wg, bc4, cnt);
    hipLaunchKernelGGL(seg_kernel, dim3(NBATCH), dim3(256), 0, stream, M, segs, cnt);
    hipLaunchKernelGGL(sort_kernel, dim3(1), dim3(256), 0, stream, segs, ssort, cnt);
    hipLaunchKernelGGL(lstm_kernel, dim3(256), dim3(256), 0, stream,
                       obs, S, M, Wg, bc4, ssort, cnt, out);
}